// Round 6
// baseline (3547.216 us; speedup 1.0000x reference)
//
#include <hip/hip_runtime.h>
#include <hip/hip_cooperative_groups.h>

namespace cg = cooperative_groups;

typedef __attribute__((ext_vector_type(8))) short bf16x8;
typedef __attribute__((ext_vector_type(4))) float f32x4;

#define T_STEPS 96
#define BATCH 64
#define HID 2048

#define AS1 __attribute__((address_space(1)))
#define AS3 __attribute__((address_space(3)))

__device__ inline unsigned short f2bf(float f) {
  union { float f; unsigned u; } x; x.f = f;
  unsigned r = x.u + 0x7fffu + ((x.u >> 16) & 1u);
  return (unsigned short)(r >> 16);
}
__device__ inline float bf2f(unsigned short b) {
  union { unsigned u; float f; } x; x.u = ((unsigned)b) << 16;
  return x.f;
}
__device__ inline float sigm(float x) { return 1.f / (1.f + __expf(-x)); }
__device__ inline float tanh_(float x) { return 1.f - 2.f / (__expf(2.f * x) + 1.f); }

// ---------------------------------------------------------------- cast f32->bf16
__global__ __launch_bounds__(256) void cast_bf16(const float* __restrict__ in,
                                                 unsigned short* __restrict__ out,
                                                 int n4) {
  int i = blockIdx.x * 256 + threadIdx.x;
  if (i >= n4) return;
  float4 v = ((const float4*)in)[i];
  ushort4 o;
  o.x = f2bf(v.x); o.y = f2bf(v.y); o.z = f2bf(v.z); o.w = f2bf(v.w);
  ((ushort4*)out)[i] = o;
}

// ---------------------------------------------------------------- gumbel (threefry, partitionable)
__global__ void gumbel_k(float* __restrict__ g) {
  int p = blockIdx.x * blockDim.x + threadIdx.x;
  if (p >= 12288) return;
  const unsigned k1 = 0u, k2 = 42u;
  unsigned ks[3] = { k1, k2, 0x1BD11BDAu ^ k1 ^ k2 };
  unsigned x0 = 0u + ks[0];
  unsigned x1 = (unsigned)p + ks[1];
  const int rot[2][4] = { {13, 15, 26, 6}, {17, 29, 16, 24} };
  #pragma unroll
  for (int i = 0; i < 5; ++i) {
    #pragma unroll
    for (int j = 0; j < 4; ++j) {
      int r = rot[i & 1][j];
      x0 += x1;
      x1 = (x1 << r) | (x1 >> (32 - r));
      x1 ^= x0;
    }
    x0 += ks[(i + 1) % 3];
    x1 += ks[(i + 2) % 3] + (unsigned)(i + 1);
  }
  unsigned bits = x0 ^ x1;
  union { unsigned u; float f; } v; v.u = (bits >> 9) | 0x3f800000u;
  float f = v.f - 1.f;
  const float tiny = 1.17549435e-38f;
  float u = fmaxf(tiny, f * (1.f - tiny) + tiny);
  g[p] = -logf(-logf(u));
}

// ---------------------------------------------------------------- phase-1 GEMM (unchanged)
__global__ __launch_bounds__(256) void gemm_xg(
    const unsigned short* __restrict__ A,
    const unsigned short* __restrict__ W,
    const float* __restrict__ b_ih, const float* __restrict__ b_hh,
    unsigned short* __restrict__ xg) {
  __shared__ unsigned short As[128 * 32];
  __shared__ unsigned short Bs[128 * 32];
  int bid = blockIdx.x;
  int nb = bid & 63, mb = bid >> 6;
  int m0 = mb * 128, n0 = nb * 128;
  int tid = threadIdx.x, w = tid >> 6, l = tid & 63;
  int lr = l & 15, lg = l >> 4;
  int wm = (w & 1) * 64, wn = (w >> 1) * 64;
  f32x4 acc[4][4] = {};
  int e0 = w * 512 + l * 8;
  for (int k0 = 0; k0 < 2048; k0 += 32) {
    __syncthreads();
    #pragma unroll
    for (int j = 0; j < 2; ++j) {
      int e = j * 2048 + e0;
      int r = e >> 5, c = e & 31;
      const unsigned short* ga = A + (long)(m0 + r) * 2048 + k0 + c;
      const unsigned short* gb = W + (long)(n0 + r) * 2048 + k0 + c;
      __builtin_amdgcn_global_load_lds(
          (const AS1 unsigned int*)ga,
          (AS3 unsigned int*)&As[j * 2048 + w * 512], 16, 0, 0);
      __builtin_amdgcn_global_load_lds(
          (const AS1 unsigned int*)gb,
          (AS3 unsigned int*)&Bs[j * 2048 + w * 512], 16, 0, 0);
    }
    __syncthreads();
    bf16x8 av[4], bv[4];
    #pragma unroll
    for (int i = 0; i < 4; ++i)
      av[i] = *(const bf16x8*)&As[(wm + i * 16 + lr) * 32 + lg * 8];
    #pragma unroll
    for (int i = 0; i < 4; ++i)
      bv[i] = *(const bf16x8*)&Bs[(wn + i * 16 + lr) * 32 + lg * 8];
    #pragma unroll
    for (int i = 0; i < 4; ++i)
      #pragma unroll
      for (int j = 0; j < 4; ++j)
        acc[i][j] = __builtin_amdgcn_mfma_f32_16x16x32_bf16(av[i], bv[j], acc[i][j], 0, 0, 0);
  }
  #pragma unroll
  for (int j = 0; j < 4; ++j) {
    int n = n0 + wn + j * 16 + lr;
    float bias = b_ih[n] + b_hh[n];
    #pragma unroll
    for (int i = 0; i < 4; ++i) {
      #pragma unroll
      for (int r = 0; r < 4; ++r) {
        int m = m0 + wm + i * 16 + lg * 4 + r;
        int bb = m / 96;
        int tt = m - bb * 96;
        long row = (long)tt * 64 + bb;
        xg[row * 8192 + n] = f2bf(acc[i][j][r] + bias);
      }
    }
  }
}

// ---------------------------------------------------------------- persistent recurrence
// Cooperative kernel, grid 256 = [mh:2][nb:128], block 512 = 8 waves, 1 block/CU.
// Block tile: 32 batches (mh half) x 64 gate-rows (4 gates x 16 h-cols nb*16..+16).
// Wave w owns K-slices {c*1024 + w*128 .. +128 : c=0,1}; its W_hh fragments live
// PERMANENTLY in 128 VGPRs (loaded once). Per step: stage H-half into 2x64KB LDS
// chunks (XOR-swizzled via pre-swizzled source), counted vmcnt, 64 MFMA/wave,
// K-partial combine in LDS (aliases chunk0), fused cell update with c in a
// REGISTER, grid-wide sync.
__global__ __launch_bounds__(512, 2) void lstm_persist(
    const unsigned short* __restrict__ Whh,   // (8192,2048) bf16
    const unsigned short* __restrict__ xg,    // (96,64,8192) bf16
    unsigned short* __restrict__ Hall,        // (97,64,2048) bf16
    unsigned short* __restrict__ Call) {      // (96,64,2048) bf16
  extern __shared__ unsigned char smem[];     // 128 KB: chunk0 64K | chunk1 64K
  cg::grid_group grid = cg::this_grid();

  const int bid = blockIdx.x;
  const int mh = bid >> 7;            // batch half
  const int nb = bid & 127;           // 16 h-cols
  const int tid = threadIdx.x;
  const int w = tid >> 6, l = tid & 63;
  const int lr = l & 15, lg = l >> 4;

  // ---- W_hh fragments -> registers (once). b[c][ks][nf], all indexing static.
  bf16x8 bfr[2][4][4];
  #pragma unroll
  for (int c = 0; c < 2; ++c)
    #pragma unroll
    for (int ks = 0; ks < 4; ++ks)
      #pragma unroll
      for (int nf = 0; nf < 4; ++nf) {
        long row = (long)nf * 2048 + nb * 16 + lr;          // nf = gate
        long k = (long)c * 1024 + w * 128 + ks * 32 + lg * 8;
        bfr[c][ks][nf] = *(const bf16x8*)(Whh + row * 2048 + k);
      }

  // epilogue cell: one per thread (32 batches x 16 cols)
  const int eb = tid >> 4;            // 0..31
  const int ej = tid & 15;            // 0..15
  const int batch = mh * 32 + eb;
  const int col = nb * 16 + ej;
  float creg = 0.f;

  for (int t = 0; t < T_STEPS; ++t) {
    const unsigned short* Hp = Hall + (long)t * BATCH * HID;

    // ---- stage both chunks (linear LDS dest, inverse-swizzled global source)
    #pragma unroll
    for (int c = 0; c < 2; ++c) {
      #pragma unroll
      for (int i = 0; i < 8; ++i) {
        int slot = i * 512 + tid;             // 16B slots
        int row = slot >> 7;                  // 0..31
        int klin = (slot & 127) * 16;         // byte offset in row (1024 K * 2B)
        int ksrc = klin ^ ((row & 7) << 4);
        const unsigned short* src =
            Hp + (long)(mh * 32 + row) * 2048 + c * 1024 + (ksrc >> 1);
        __builtin_amdgcn_global_load_lds((const AS1 unsigned int*)src,
            (AS3 unsigned int*)(smem + c * 65536 + slot * 16), 16, 0, 0);
      }
      __builtin_amdgcn_sched_barrier(0);
    }
    // xg prefetch (4 scalar bf16) — in flight under chunk-0 compute
    const unsigned short* xr = xg + ((long)t * 64 + batch) * 8192 + col;
    unsigned short x0v = xr[0];
    unsigned short x1v = xr[2048];
    unsigned short x2v = xr[4096];
    unsigned short x3v = xr[6144];
    __builtin_amdgcn_sched_barrier(0);

    f32x4 acc0[4] = {}, acc1[4] = {};         // [nf] for mf=0 / mf=1

    // chunk 0 ready (8 oldest of >=20 outstanding complete at vmcnt<=12)
    asm volatile("s_waitcnt vmcnt(12)" ::: "memory");
    __builtin_amdgcn_s_barrier();
    __builtin_amdgcn_sched_barrier(0);
    {
      const unsigned char* base = smem;
      __builtin_amdgcn_s_setprio(1);
      #pragma unroll
      for (int ks = 0; ks < 4; ++ks) {
        int kb = (w * 256 + ks * 64 + lg * 16) ^ ((lr & 7) << 4);
        bf16x8 a0 = *(const bf16x8*)(base + (lr) * 2048 + kb);
        bf16x8 a1 = *(const bf16x8*)(base + (16 + lr) * 2048 + kb);
        #pragma unroll
        for (int nf = 0; nf < 4; ++nf) {
          acc0[nf] = __builtin_amdgcn_mfma_f32_16x16x32_bf16(a0, bfr[0][ks][nf], acc0[nf], 0, 0, 0);
          acc1[nf] = __builtin_amdgcn_mfma_f32_16x16x32_bf16(a1, bfr[0][ks][nf], acc1[nf], 0, 0, 0);
        }
      }
      __builtin_amdgcn_s_setprio(0);
    }
    __builtin_amdgcn_sched_barrier(0);
    // chunk 1 ready
    asm volatile("s_waitcnt vmcnt(4)" ::: "memory");
    __builtin_amdgcn_s_barrier();
    __builtin_amdgcn_sched_barrier(0);
    {
      const unsigned char* base = smem + 65536;
      __builtin_amdgcn_s_setprio(1);
      #pragma unroll
      for (int ks = 0; ks < 4; ++ks) {
        int kb = (w * 256 + ks * 64 + lg * 16) ^ ((lr & 7) << 4);
        bf16x8 a0 = *(const bf16x8*)(base + (lr) * 2048 + kb);
        bf16x8 a1 = *(const bf16x8*)(base + (16 + lr) * 2048 + kb);
        #pragma unroll
        for (int nf = 0; nf < 4; ++nf) {
          acc0[nf] = __builtin_amdgcn_mfma_f32_16x16x32_bf16(a0, bfr[1][ks][nf], acc0[nf], 0, 0, 0);
          acc1[nf] = __builtin_amdgcn_mfma_f32_16x16x32_bf16(a1, bfr[1][ks][nf], acc1[nf], 0, 0, 0);
        }
      }
      __builtin_amdgcn_s_setprio(0);
    }
    __syncthreads();   // full drain; chunk0 area now reusable

    // ---- K-partials -> LDS (alias chunk0): [w:8][nn:64][b:32, ^((nn&7)<<2)]
    float* part = (float*)smem;
    #pragma unroll
    for (int nf = 0; nf < 4; ++nf) {
      const int nn = nf * 16 + lr;
      const int bsw = (lr & 7) << 2;
      {
        const int b0 = (0 + lg * 4) ^ bsw;                 // mf = 0
        *(f32x4*)&part[(w * 64 + nn) * 32 + b0] = acc0[nf];
      }
      {
        const int b0 = (16 + lg * 4) ^ bsw;                // mf = 1
        *(f32x4*)&part[(w * 64 + nn) * 32 + b0] = acc1[nf];
      }
    }
    __syncthreads();

    // ---- combine 8 K-partials + fused LSTM cell update (c stays in register)
    float sum[4];
    #pragma unroll
    for (int g4 = 0; g4 < 4; ++g4) {
      const int nn = g4 * 16 + ej;
      const int bx = eb ^ ((ej & 7) << 2);
      float s = 0.f;
      #pragma unroll
      for (int ww = 0; ww < 8; ++ww) s += part[(ww * 64 + nn) * 32 + bx];
      sum[g4] = s;
    }
    const float iv = sum[0] + bf2f(x0v);
    const float fv = sum[1] + bf2f(x1v);
    const float gv = sum[2] + bf2f(x2v);
    const float ov = sum[3] + bf2f(x3v);
    creg = sigm(fv) * creg + sigm(iv) * tanh_(gv);
    const float h = sigm(ov) * tanh_(creg);
    Call[((long)t * 64 + batch) * 2048 + col] = f2bf(creg);
    Hall[((long)(t + 1) * 64 + batch) * 2048 + col] = f2bf(h);

    grid.sync();
  }
}

// ---------------------------------------------------------------- heads (unchanged)
__global__ __launch_bounds__(256) void heads(
    const unsigned short* __restrict__ Hall,
    const unsigned short* __restrict__ Call,
    const float* __restrict__ Wp, const float* __restrict__ bp,
    const float* __restrict__ Wpc, const float* __restrict__ bpc,
    const float* __restrict__ Wu, const float* __restrict__ bu,
    const float* __restrict__ Wuse, const float* __restrict__ buse,
    const float* __restrict__ gum,
    float* __restrict__ out) {
  int p = blockIdx.x * 4 + (threadIdx.x >> 6);
  int l = threadIdx.x & 63;
  int t = p >> 6, b = p & 63;
  const unsigned short* h = Hall + ((long)(t + 1) * 64 + b) * 2048;
  const unsigned short* c = Call + ((long)t * 64 + b) * 2048;
  float s0 = 0, s1 = 0, sc0 = 0, sc1 = 0, su = 0, q0 = 0, q1 = 0;
  #pragma unroll
  for (int j = 0; j < 8; ++j) {
    int k = j * 256 + l * 4;
    ushort4 hv = *(const ushort4*)(h + k);
    ushort4 cv = *(const ushort4*)(c + k);
    float hf0 = bf2f(hv.x), hf1 = bf2f(hv.y), hf2 = bf2f(hv.z), hf3 = bf2f(hv.w);
    float cf0 = bf2f(cv.x), cf1 = bf2f(cv.y), cf2 = bf2f(cv.z), cf3 = bf2f(cv.w);
    float4 w0 = *(const float4*)(Wp + k);
    float4 w1 = *(const float4*)(Wp + 2048 + k);
    float4 w2 = *(const float4*)(Wpc + k);
    float4 w3 = *(const float4*)(Wpc + 2048 + k);
    float4 w4 = *(const float4*)(Wu + k);
    float4 w5 = *(const float4*)(Wuse + k);
    float4 w6 = *(const float4*)(Wuse + 2048 + k);
    s0 += hf0 * w0.x + hf1 * w0.y + hf2 * w0.z + hf3 * w0.w;
    s1 += hf0 * w1.x + hf1 * w1.y + hf2 * w1.z + hf3 * w1.w;
    sc0 += cf0 * w2.x + cf1 * w2.y + cf2 * w2.z + cf3 * w2.w;
    sc1 += cf0 * w3.x + cf1 * w3.y + cf2 * w3.z + cf3 * w3.w;
    su += hf0 * w4.x + hf1 * w4.y + hf2 * w4.z + hf3 * w4.w;
    q0 += hf0 * w5.x + hf1 * w5.y + hf2 * w5.z + hf3 * w5.w;
    q1 += hf0 * w6.x + hf1 * w6.y + hf2 * w6.z + hf3 * w6.w;
  }
  #pragma unroll
  for (int off = 32; off > 0; off >>= 1) {
    s0 += __shfl_xor(s0, off);
    s1 += __shfl_xor(s1, off);
    sc0 += __shfl_xor(sc0, off);
    sc1 += __shfl_xor(sc1, off);
    su += __shfl_xor(su, off);
    q0 += __shfl_xor(q0, off);
    q1 += __shfl_xor(q1, off);
  }
  if (l == 0) {
    out[(p << 1)] = s0 + bp[0];
    out[(p << 1) + 1] = s1 + bp[1];
    out[12288 + (p << 1)] = sc0 + bpc[0];
    out[12288 + (p << 1) + 1] = sc1 + bpc[1];
    out[24576 + p] = su + bu[0];
    float u0 = q0 + buse[0] + gum[p * 2];
    float u1 = q1 + buse[1] + gum[p * 2 + 1];
    float m = fmaxf(u0, u1);
    float x0 = expf(u0 - m), x1 = expf(u1 - m);
    float inv = 1.f / (x0 + x1);
    if (t >= 1) {
      out[30720 + ((t - 1) * 64 + b) * 2] = x0 * inv;
      out[30720 + ((t - 1) * 64 + b) * 2 + 1] = x1 * inv;
    }
  }
}

// ---------------------------------------------------------------- launch
extern "C" void kernel_launch(void* const* d_in, const int* in_sizes, int n_in,
                              void* d_out, int out_size, void* d_ws, size_t ws_size,
                              hipStream_t stream) {
  const float* feature  = (const float*)d_in[0];
  const float* W_ih     = (const float*)d_in[1];
  const float* W_hh     = (const float*)d_in[2];
  const float* b_ih     = (const float*)d_in[3];
  const float* b_hh     = (const float*)d_in[4];
  const float* W_pred   = (const float*)d_in[5];
  const float* b_pred   = (const float*)d_in[6];
  const float* W_pred_c = (const float*)d_in[7];
  const float* b_pred_c = (const float*)d_in[8];
  const float* W_util   = (const float*)d_in[9];
  const float* b_util   = (const float*)d_in[10];
  const float* W_use    = (const float*)d_in[11];
  const float* b_use    = (const float*)d_in[12];

  char* ws = (char*)d_ws;
  unsigned short* Abf  = (unsigned short*)(ws + 0);
  unsigned short* Call = (unsigned short*)(ws + 0);       // aliases Abf after phase 1
  unsigned short* Wbf  = (unsigned short*)(ws + 25165824L);
  unsigned short* xg   = (unsigned short*)(ws + 58720256L);
  unsigned short* Hall = (unsigned short*)(ws + 159383552L);
  float* gum           = (float*)(ws + 185335808L);
  float* out = (float*)d_out;

  hipMemsetAsync(Hall, 0, (size_t)BATCH * HID * 2, stream);

  gumbel_k<<<48, 256, 0, stream>>>(gum);

  cast_bf16<<<(12582912 / 4) / 256, 256, 0, stream>>>(feature, Abf, 12582912 / 4);
  cast_bf16<<<(16777216 / 4) / 256, 256, 0, stream>>>(W_ih, Wbf, 16777216 / 4);

  gemm_xg<<<3072, 256, 0, stream>>>(Abf, Wbf, b_ih, b_hh, xg);

  cast_bf16<<<(16777216 / 4) / 256, 256, 0, stream>>>(W_hh, Wbf, 16777216 / 4);

  // persistent recurrence (cooperative)
  {
    const unsigned short* WhhArg = Wbf;
    const unsigned short* xgArg  = xg;
    unsigned short* HallArg = Hall;
    unsigned short* CallArg = Call;
    void* args[] = { (void*)&WhhArg, (void*)&xgArg, (void*)&HallArg, (void*)&CallArg };
    hipLaunchCooperativeKernel((const void*)lstm_persist, dim3(256), dim3(512),
                               args, 131072, stream);
  }

  heads<<<1536, 256, 0, stream>>>(Hall, Call,
                                  W_pred, b_pred, W_pred_c, b_pred_c,
                                  W_util, b_util, W_use, b_use,
                                  gum, out);
}

// Round 7
// 1622.028 us; speedup vs baseline: 2.1869x; 2.1869x over previous
//
#include <hip/hip_runtime.h>

typedef __attribute__((ext_vector_type(8))) short bf16x8;
typedef __attribute__((ext_vector_type(4))) float f32x4;

#define T_STEPS 96
#define BATCH 64
#define HID 2048

#define AS1 __attribute__((address_space(1)))
#define AS3 __attribute__((address_space(3)))

__device__ inline unsigned short f2bf(float f) {
  union { float f; unsigned u; } x; x.f = f;
  unsigned r = x.u + 0x7fffu + ((x.u >> 16) & 1u);
  return (unsigned short)(r >> 16);
}
__device__ inline float bf2f(unsigned short b) {
  union { unsigned u; float f; } x; x.u = ((unsigned)b) << 16;
  return x.f;
}
__device__ inline float sigm(float x) { return 1.f / (1.f + __expf(-x)); }
__device__ inline float tanh_(float x) { return 1.f - 2.f / (__expf(2.f * x) + 1.f); }

// ---------------------------------------------------------------- cast f32->bf16
__global__ __launch_bounds__(256) void cast_bf16(const float* __restrict__ in,
                                                 unsigned short* __restrict__ out,
                                                 int n4) {
  int i = blockIdx.x * 256 + threadIdx.x;
  if (i >= n4) return;
  float4 v = ((const float4*)in)[i];
  ushort4 o;
  o.x = f2bf(v.x); o.y = f2bf(v.y); o.z = f2bf(v.z); o.w = f2bf(v.w);
  ((ushort4*)out)[i] = o;
}

// ---------------------------------------------------------------- gumbel (threefry, partitionable)
__global__ void gumbel_k(float* __restrict__ g) {
  int p = blockIdx.x * blockDim.x + threadIdx.x;
  if (p >= 12288) return;
  const unsigned k1 = 0u, k2 = 42u;
  unsigned ks[3] = { k1, k2, 0x1BD11BDAu ^ k1 ^ k2 };
  unsigned x0 = 0u + ks[0];
  unsigned x1 = (unsigned)p + ks[1];
  const int rot[2][4] = { {13, 15, 26, 6}, {17, 29, 16, 24} };
  #pragma unroll
  for (int i = 0; i < 5; ++i) {
    #pragma unroll
    for (int j = 0; j < 4; ++j) {
      int r = rot[i & 1][j];
      x0 += x1;
      x1 = (x1 << r) | (x1 >> (32 - r));
      x1 ^= x0;
    }
    x0 += ks[(i + 1) % 3];
    x1 += ks[(i + 2) % 3] + (unsigned)(i + 1);
  }
  unsigned bits = x0 ^ x1;
  union { unsigned u; float f; } v; v.u = (bits >> 9) | 0x3f800000u;
  float f = v.f - 1.f;
  const float tiny = 1.17549435e-38f;
  float u = fmaxf(tiny, f * (1.f - tiny) + tiny);
  g[p] = -logf(-logf(u));
}

// ---------------------------------------------------------------- phase-1 GEMM (unchanged)
__global__ __launch_bounds__(256) void gemm_xg(
    const unsigned short* __restrict__ A,
    const unsigned short* __restrict__ W,
    const float* __restrict__ b_ih, const float* __restrict__ b_hh,
    unsigned short* __restrict__ xg) {
  __shared__ unsigned short As[128 * 32];
  __shared__ unsigned short Bs[128 * 32];
  int bid = blockIdx.x;
  int nb = bid & 63, mb = bid >> 6;
  int m0 = mb * 128, n0 = nb * 128;
  int tid = threadIdx.x, w = tid >> 6, l = tid & 63;
  int lr = l & 15, lg = l >> 4;
  int wm = (w & 1) * 64, wn = (w >> 1) * 64;
  f32x4 acc[4][4] = {};
  int e0 = w * 512 + l * 8;
  for (int k0 = 0; k0 < 2048; k0 += 32) {
    __syncthreads();
    #pragma unroll
    for (int j = 0; j < 2; ++j) {
      int e = j * 2048 + e0;
      int r = e >> 5, c = e & 31;
      const unsigned short* ga = A + (long)(m0 + r) * 2048 + k0 + c;
      const unsigned short* gb = W + (long)(n0 + r) * 2048 + k0 + c;
      __builtin_amdgcn_global_load_lds(
          (const AS1 unsigned int*)ga,
          (AS3 unsigned int*)&As[j * 2048 + w * 512], 16, 0, 0);
      __builtin_amdgcn_global_load_lds(
          (const AS1 unsigned int*)gb,
          (AS3 unsigned int*)&Bs[j * 2048 + w * 512], 16, 0, 0);
    }
    __syncthreads();
    bf16x8 av[4], bv[4];
    #pragma unroll
    for (int i = 0; i < 4; ++i)
      av[i] = *(const bf16x8*)&As[(wm + i * 16 + lr) * 32 + lg * 8];
    #pragma unroll
    for (int i = 0; i < 4; ++i)
      bv[i] = *(const bf16x8*)&Bs[(wn + i * 16 + lr) * 32 + lg * 8];
    #pragma unroll
    for (int i = 0; i < 4; ++i)
      #pragma unroll
      for (int j = 0; j < 4; ++j)
        acc[i][j] = __builtin_amdgcn_mfma_f32_16x16x32_bf16(av[i], bv[j], acc[i][j], 0, 0, 0);
  }
  #pragma unroll
  for (int j = 0; j < 4; ++j) {
    int n = n0 + wn + j * 16 + lr;
    float bias = b_ih[n] + b_hh[n];
    #pragma unroll
    for (int i = 0; i < 4; ++i) {
      #pragma unroll
      for (int r = 0; r < 4; ++r) {
        int m = m0 + wm + i * 16 + lg * 4 + r;
        int bb = m / 96;
        int tt = m - bb * 96;
        long row = (long)tt * 64 + bb;
        xg[row * 8192 + n] = f2bf(acc[i][j][r] + bias);
      }
    }
  }
}

// ---------------------------------------------------------------- recurrent step
// grid 256 (block cb: 8 h-cols x 4 gates = 32 W-rows, all 64 batches).
// Block K is split into 4 chunks of 512; wave w owns sub-slice [c*512+w*64, +64).
// Per chunk: H staged into 64KB LDS ring buffer (XOR-swizzled source, linear
// dest), W frags (4 bf16x8/wave) global->VGPR prefetched one chunk ahead,
// 8 ds_read_b128 -> 16 MFMA per wave (0.5 reads/MFMA). Full-drain vmcnt(0) +
// barrier per chunk (T3 minimal). K-partials combined across waves via LDS
// (aliases buf0), fused gate/c/h epilogue.
__global__ __launch_bounds__(512) void lstm_step(
    const unsigned short* __restrict__ Whh,   // (8192,2048) bf16
    const unsigned short* __restrict__ xg,    // (96,64,8192) bf16
    const unsigned short* __restrict__ Hprev, // (64,2048) bf16
    unsigned short* __restrict__ Hnext,       // (64,2048) bf16
    unsigned short* __restrict__ Call_t,      // (64,2048) bf16 snapshot
    float* __restrict__ Cstate,               // (64,2048) f32
    int t) {
  extern __shared__ unsigned char smem[];     // 128 KB: buf0 64K | buf1 64K
  const int cb = blockIdx.x;
  const int tid = threadIdx.x;
  const int w = tid >> 6, l = tid & 63;
  const int lr = l & 15, lg = l >> 4;

  // ---- epilogue prefetch: xg gates + Cstate for this thread's cell
  const int eb = tid >> 3;                    // batch 0..63
  const int ej = tid & 7;                     // col 0..7
  const unsigned short* xrow = xg + ((long)t * 64 + eb) * 8192 + cb * 8 + ej;
  const unsigned short x_i = xrow[0];
  const unsigned short x_f = xrow[2048];
  const unsigned short x_g = xrow[4096];
  const unsigned short x_o = xrow[6144];
  const long ci = (long)eb * 2048 + cb * 8 + ej;
  const float cprev = Cstate[ci];

  // ---- staging addressing: 8 gload_lds/thread/chunk, 64KB chunk = 64 rows x 1024B
  // slot = i*512 + tid; row = slot>>6; u16 = slot&63 (16B unit in 1024B window)
  // source byte in window: (u16*16) ^ ((row&7)<<4)  [inverse-swizzle]
#define STAGE(bufsel, c) do {                                                   \
    _Pragma("unroll")                                                           \
    for (int i_ = 0; i_ < 8; ++i_) {                                            \
      int slot_ = i_ * 512 + tid;                                               \
      int row_ = slot_ >> 6;                                                    \
      int ksrc_ = ((slot_ & 63) * 16) ^ ((row_ & 7) << 4);                      \
      const unsigned short* src_ =                                              \
          Hprev + (long)row_ * 2048 + (c) * 512 + (ksrc_ >> 1);                 \
      __builtin_amdgcn_global_load_lds((const AS1 unsigned int*)src_,           \
          (AS3 unsigned int*)(smem + (bufsel) * 65536 + slot_ * 16), 16, 0, 0); \
    }                                                                           \
  } while (0)

  // W frag global address: frag(ks,nf): row nn = nf*16+lr -> gate (nn>>3), col cb*8+(nn&7)
  // k = c*512 + w*64 + ks*32 + lg*8
  const long wr0 = ((long)((lr >> 3)) * 2048 + cb * 8 + (lr & 7)) * 2048;          // nf=0
  const long wr1 = ((long)(((16 + lr) >> 3)) * 2048 + cb * 8 + (lr & 7)) * 2048;   // nf=1
  const int kwbase = w * 64 + lg * 8;
#define LOAD_W(c, d00, d01, d10, d11) do {                                      \
    const unsigned short* wp_ = Whh + (long)(c) * 512 + kwbase;                 \
    d00 = *(const bf16x8*)(wp_ + wr0);                                          \
    d01 = *(const bf16x8*)(wp_ + wr1);                                          \
    d10 = *(const bf16x8*)(wp_ + wr0 + 32);                                     \
    d11 = *(const bf16x8*)(wp_ + wr1 + 32);                                     \
  } while (0)

  // per-chunk compute: 8 ds_read_b128 + 16 MFMA
  f32x4 acc[4][2] = {};
  const int kx = (lr & 7) << 4;
#define COMPUTE(bufsel, b00, b01, b10, b11) do {                                \
    const unsigned char* base_ = smem + (bufsel) * 65536;                       \
    _Pragma("unroll")                                                           \
    for (int mf_ = 0; mf_ < 4; ++mf_) {                                         \
      const unsigned char* rp_ = base_ + (mf_ * 16 + lr) * 1024;                \
      int kb0_ = (w * 128 + lg * 16) ^ kx;                                      \
      int kb1_ = (w * 128 + 64 + lg * 16) ^ kx;                                 \
      bf16x8 a0_ = *(const bf16x8*)(rp_ + kb0_);                                \
      bf16x8 a1_ = *(const bf16x8*)(rp_ + kb1_);                                \
      acc[mf_][0] = __builtin_amdgcn_mfma_f32_16x16x32_bf16(a0_, b00, acc[mf_][0], 0, 0, 0); \
      acc[mf_][1] = __builtin_amdgcn_mfma_f32_16x16x32_bf16(a0_, b01, acc[mf_][1], 0, 0, 0); \
      acc[mf_][0] = __builtin_amdgcn_mfma_f32_16x16x32_bf16(a1_, b10, acc[mf_][0], 0, 0, 0); \
      acc[mf_][1] = __builtin_amdgcn_mfma_f32_16x16x32_bf16(a1_, b11, acc[mf_][1], 0, 0, 0); \
    }                                                                           \
  } while (0)

#define DRAIN() do {                                                            \
    __builtin_amdgcn_sched_barrier(0);                                          \
    asm volatile("s_waitcnt vmcnt(0)" ::: "memory");                            \
    __builtin_amdgcn_s_barrier();                                               \
    __builtin_amdgcn_sched_barrier(0);                                          \
  } while (0)

  bf16x8 cw00, cw01, cw10, cw11;   // current chunk W frags
  bf16x8 nw00, nw01, nw10, nw11;   // next chunk W frags

  STAGE(0, 0);
  LOAD_W(0, cw00, cw01, cw10, cw11);
  DRAIN();

  // chunk 0
  STAGE(1, 1);
  LOAD_W(1, nw00, nw01, nw10, nw11);
  __builtin_amdgcn_s_setprio(1);
  COMPUTE(0, cw00, cw01, cw10, cw11);
  __builtin_amdgcn_s_setprio(0);
  DRAIN();
  cw00 = nw00; cw01 = nw01; cw10 = nw10; cw11 = nw11;

  // chunk 1
  STAGE(0, 2);
  LOAD_W(2, nw00, nw01, nw10, nw11);
  __builtin_amdgcn_s_setprio(1);
  COMPUTE(1, cw00, cw01, cw10, cw11);
  __builtin_amdgcn_s_setprio(0);
  DRAIN();
  cw00 = nw00; cw01 = nw01; cw10 = nw10; cw11 = nw11;

  // chunk 2
  STAGE(1, 3);
  LOAD_W(3, nw00, nw01, nw10, nw11);
  __builtin_amdgcn_s_setprio(1);
  COMPUTE(0, cw00, cw01, cw10, cw11);
  __builtin_amdgcn_s_setprio(0);
  DRAIN();
  cw00 = nw00; cw01 = nw01; cw10 = nw10; cw11 = nw11;

  // chunk 3 (no prefetch)
  __builtin_amdgcn_s_setprio(1);
  COMPUTE(1, cw00, cw01, cw10, cw11);
  __builtin_amdgcn_s_setprio(0);
  __syncthreads();

#undef STAGE
#undef LOAD_W
#undef COMPUTE
#undef DRAIN

  // ---- K-partials -> LDS (alias buf0): [w:8][nn:32][batch:64 ^ ((nn&7)<<3)]
  float* part = (float*)smem;
  #pragma unroll
  for (int nf = 0; nf < 2; ++nf) {
    const int nn = nf * 16 + lr;
    const int bx = (lr & 7) << 3;
    #pragma unroll
    for (int mf = 0; mf < 4; ++mf) {
      const int b0 = (mf * 16 + lg * 4) ^ bx;
      *(f32x4*)&part[(w * 32 + nn) * 64 + b0] = acc[mf][nf];
    }
  }
  __syncthreads();

  // ---- combine 8 K-partials + fused LSTM cell update
  float sum[4];
  #pragma unroll
  for (int g = 0; g < 4; ++g) {
    const int nn = g * 8 + ej;
    const int base = nn * 64 + (eb ^ (ej << 3));
    float s = 0.f;
    #pragma unroll
    for (int ww = 0; ww < 8; ++ww) s += part[ww * 2048 + base];
    sum[g] = s;
  }
  const float iv = sum[0] + bf2f(x_i);
  const float fv = sum[1] + bf2f(x_f);
  const float gv = sum[2] + bf2f(x_g);
  const float ov = sum[3] + bf2f(x_o);
  const float c = sigm(fv) * cprev + sigm(iv) * tanh_(gv);
  const float h = sigm(ov) * tanh_(c);
  Cstate[ci] = c;
  Call_t[ci] = f2bf(c);
  Hnext[ci] = f2bf(h);
}

// ---------------------------------------------------------------- heads (unchanged)
__global__ __launch_bounds__(256) void heads(
    const unsigned short* __restrict__ Hall,
    const unsigned short* __restrict__ Call,
    const float* __restrict__ Wp, const float* __restrict__ bp,
    const float* __restrict__ Wpc, const float* __restrict__ bpc,
    const float* __restrict__ Wu, const float* __restrict__ bu,
    const float* __restrict__ Wuse, const float* __restrict__ buse,
    const float* __restrict__ gum,
    float* __restrict__ out) {
  int p = blockIdx.x * 4 + (threadIdx.x >> 6);
  int l = threadIdx.x & 63;
  int t = p >> 6, b = p & 63;
  const unsigned short* h = Hall + ((long)(t + 1) * 64 + b) * 2048;
  const unsigned short* c = Call + ((long)t * 64 + b) * 2048;
  float s0 = 0, s1 = 0, sc0 = 0, sc1 = 0, su = 0, q0 = 0, q1 = 0;
  #pragma unroll
  for (int j = 0; j < 8; ++j) {
    int k = j * 256 + l * 4;
    ushort4 hv = *(const ushort4*)(h + k);
    ushort4 cv = *(const ushort4*)(c + k);
    float hf0 = bf2f(hv.x), hf1 = bf2f(hv.y), hf2 = bf2f(hv.z), hf3 = bf2f(hv.w);
    float cf0 = bf2f(cv.x), cf1 = bf2f(cv.y), cf2 = bf2f(cv.z), cf3 = bf2f(cv.w);
    float4 w0 = *(const float4*)(Wp + k);
    float4 w1 = *(const float4*)(Wp + 2048 + k);
    float4 w2 = *(const float4*)(Wpc + k);
    float4 w3 = *(const float4*)(Wpc + 2048 + k);
    float4 w4 = *(const float4*)(Wu + k);
    float4 w5 = *(const float4*)(Wuse + k);
    float4 w6 = *(const float4*)(Wuse + 2048 + k);
    s0 += hf0 * w0.x + hf1 * w0.y + hf2 * w0.z + hf3 * w0.w;
    s1 += hf0 * w1.x + hf1 * w1.y + hf2 * w1.z + hf3 * w1.w;
    sc0 += cf0 * w2.x + cf1 * w2.y + cf2 * w2.z + cf3 * w2.w;
    sc1 += cf0 * w3.x + cf1 * w3.y + cf2 * w3.z + cf3 * w3.w;
    su += hf0 * w4.x + hf1 * w4.y + hf2 * w4.z + hf3 * w4.w;
    q0 += hf0 * w5.x + hf1 * w5.y + hf2 * w5.z + hf3 * w5.w;
    q1 += hf0 * w6.x + hf1 * w6.y + hf2 * w6.z + hf3 * w6.w;
  }
  #pragma unroll
  for (int off = 32; off > 0; off >>= 1) {
    s0 += __shfl_xor(s0, off);
    s1 += __shfl_xor(s1, off);
    sc0 += __shfl_xor(sc0, off);
    sc1 += __shfl_xor(sc1, off);
    su += __shfl_xor(su, off);
    q0 += __shfl_xor(q0, off);
    q1 += __shfl_xor(q1, off);
  }
  if (l == 0) {
    out[(p << 1)] = s0 + bp[0];
    out[(p << 1) + 1] = s1 + bp[1];
    out[12288 + (p << 1)] = sc0 + bpc[0];
    out[12288 + (p << 1) + 1] = sc1 + bpc[1];
    out[24576 + p] = su + bu[0];
    float u0 = q0 + buse[0] + gum[p * 2];
    float u1 = q1 + buse[1] + gum[p * 2 + 1];
    float m = fmaxf(u0, u1);
    float x0 = expf(u0 - m), x1 = expf(u1 - m);
    float inv = 1.f / (x0 + x1);
    if (t >= 1) {
      out[30720 + ((t - 1) * 64 + b) * 2] = x0 * inv;
      out[30720 + ((t - 1) * 64 + b) * 2 + 1] = x1 * inv;
    }
  }
}

// ---------------------------------------------------------------- launch
extern "C" void kernel_launch(void* const* d_in, const int* in_sizes, int n_in,
                              void* d_out, int out_size, void* d_ws, size_t ws_size,
                              hipStream_t stream) {
  const float* feature  = (const float*)d_in[0];
  const float* W_ih     = (const float*)d_in[1];
  const float* W_hh     = (const float*)d_in[2];
  const float* b_ih     = (const float*)d_in[3];
  const float* b_hh     = (const float*)d_in[4];
  const float* W_pred   = (const float*)d_in[5];
  const float* b_pred   = (const float*)d_in[6];
  const float* W_pred_c = (const float*)d_in[7];
  const float* b_pred_c = (const float*)d_in[8];
  const float* W_util   = (const float*)d_in[9];
  const float* b_util   = (const float*)d_in[10];
  const float* W_use    = (const float*)d_in[11];
  const float* b_use    = (const float*)d_in[12];

  char* ws = (char*)d_ws;
  unsigned short* Abf  = (unsigned short*)(ws + 0);
  unsigned short* Call = (unsigned short*)(ws + 0);       // aliases Abf after phase 1
  unsigned short* Wbf  = (unsigned short*)(ws + 25165824L);
  unsigned short* xg   = (unsigned short*)(ws + 58720256L);
  unsigned short* Hall = (unsigned short*)(ws + 159383552L);
  float* Cstate        = (float*)(ws + 184811520L);
  float* gum           = (float*)(ws + 185335808L);
  float* out = (float*)d_out;

  hipMemsetAsync(Hall, 0, (size_t)BATCH * HID * 2, stream);
  hipMemsetAsync(Cstate, 0, (size_t)BATCH * HID * 4, stream);

  gumbel_k<<<48, 256, 0, stream>>>(gum);

  cast_bf16<<<(12582912 / 4) / 256, 256, 0, stream>>>(feature, Abf, 12582912 / 4);
  cast_bf16<<<(16777216 / 4) / 256, 256, 0, stream>>>(W_ih, Wbf, 16777216 / 4);

  gemm_xg<<<3072, 256, 0, stream>>>(Abf, Wbf, b_ih, b_hh, xg);

  cast_bf16<<<(16777216 / 4) / 256, 256, 0, stream>>>(W_hh, Wbf, 16777216 / 4);

  for (int t = 0; t < T_STEPS; ++t) {
    lstm_step<<<256, 512, 131072, stream>>>(
        Wbf, xg,
        Hall + (long)t * BATCH * HID,
        Hall + (long)(t + 1) * BATCH * HID,
        Call + (long)t * BATCH * HID,
        Cstate, t);
  }

  heads<<<1536, 256, 0, stream>>>(Hall, Call,
                                  W_pred, b_pred, W_pred_c, b_pred_c,
                                  W_util, b_util, W_use, b_use,
                                  gum, out);
}

// Round 8
// 1526.353 us; speedup vs baseline: 2.3240x; 1.0627x over previous
//
#include <hip/hip_runtime.h>

typedef __attribute__((ext_vector_type(8))) short bf16x8;
typedef __attribute__((ext_vector_type(4))) float f32x4;

#define T_STEPS 96
#define BATCH 64
#define HID 2048

#define AS1 __attribute__((address_space(1)))
#define AS3 __attribute__((address_space(3)))

__device__ inline unsigned short f2bf(float f) {
  union { float f; unsigned u; } x; x.f = f;
  unsigned r = x.u + 0x7fffu + ((x.u >> 16) & 1u);
  return (unsigned short)(r >> 16);
}
__device__ inline float bf2f(unsigned short b) {
  union { unsigned u; float f; } x; x.u = ((unsigned)b) << 16;
  return x.f;
}
__device__ inline float sigm(float x) { return 1.f / (1.f + __expf(-x)); }
__device__ inline float tanh_(float x) { return 1.f - 2.f / (__expf(2.f * x) + 1.f); }

// ---------------------------------------------------------------- cast f32->bf16
__global__ __launch_bounds__(256) void cast_bf16(const float* __restrict__ in,
                                                 unsigned short* __restrict__ out,
                                                 int n4) {
  int i = blockIdx.x * 256 + threadIdx.x;
  if (i >= n4) return;
  float4 v = ((const float4*)in)[i];
  ushort4 o;
  o.x = f2bf(v.x); o.y = f2bf(v.y); o.z = f2bf(v.z); o.w = f2bf(v.w);
  ((ushort4*)out)[i] = o;
}

// ---------------------------------------------------------------- gumbel (threefry, partitionable)
__global__ void gumbel_k(float* __restrict__ g) {
  int p = blockIdx.x * blockDim.x + threadIdx.x;
  if (p >= 12288) return;
  const unsigned k1 = 0u, k2 = 42u;
  unsigned ks[3] = { k1, k2, 0x1BD11BDAu ^ k1 ^ k2 };
  unsigned x0 = 0u + ks[0];
  unsigned x1 = (unsigned)p + ks[1];
  const int rot[2][4] = { {13, 15, 26, 6}, {17, 29, 16, 24} };
  #pragma unroll
  for (int i = 0; i < 5; ++i) {
    #pragma unroll
    for (int j = 0; j < 4; ++j) {
      int r = rot[i & 1][j];
      x0 += x1;
      x1 = (x1 << r) | (x1 >> (32 - r));
      x1 ^= x0;
    }
    x0 += ks[(i + 1) % 3];
    x1 += ks[(i + 2) % 3] + (unsigned)(i + 1);
  }
  unsigned bits = x0 ^ x1;
  union { unsigned u; float f; } v; v.u = (bits >> 9) | 0x3f800000u;
  float f = v.f - 1.f;
  const float tiny = 1.17549435e-38f;
  float u = fmaxf(tiny, f * (1.f - tiny) + tiny);
  g[p] = -logf(-logf(u));
}

// ---------------------------------------------------------------- phase-1 GEMM (unchanged)
__global__ __launch_bounds__(256) void gemm_xg(
    const unsigned short* __restrict__ A,
    const unsigned short* __restrict__ W,
    const float* __restrict__ b_ih, const float* __restrict__ b_hh,
    unsigned short* __restrict__ xg) {
  __shared__ unsigned short As[128 * 32];
  __shared__ unsigned short Bs[128 * 32];
  int bid = blockIdx.x;
  int nb = bid & 63, mb = bid >> 6;
  int m0 = mb * 128, n0 = nb * 128;
  int tid = threadIdx.x, w = tid >> 6, l = tid & 63;
  int lr = l & 15, lg = l >> 4;
  int wm = (w & 1) * 64, wn = (w >> 1) * 64;
  f32x4 acc[4][4] = {};
  int e0 = w * 512 + l * 8;
  for (int k0 = 0; k0 < 2048; k0 += 32) {
    __syncthreads();
    #pragma unroll
    for (int j = 0; j < 2; ++j) {
      int e = j * 2048 + e0;
      int r = e >> 5, c = e & 31;
      const unsigned short* ga = A + (long)(m0 + r) * 2048 + k0 + c;
      const unsigned short* gb = W + (long)(n0 + r) * 2048 + k0 + c;
      __builtin_amdgcn_global_load_lds(
          (const AS1 unsigned int*)ga,
          (AS3 unsigned int*)&As[j * 2048 + w * 512], 16, 0, 0);
      __builtin_amdgcn_global_load_lds(
          (const AS1 unsigned int*)gb,
          (AS3 unsigned int*)&Bs[j * 2048 + w * 512], 16, 0, 0);
    }
    __syncthreads();
    bf16x8 av[4], bv[4];
    #pragma unroll
    for (int i = 0; i < 4; ++i)
      av[i] = *(const bf16x8*)&As[(wm + i * 16 + lr) * 32 + lg * 8];
    #pragma unroll
    for (int i = 0; i < 4; ++i)
      bv[i] = *(const bf16x8*)&Bs[(wn + i * 16 + lr) * 32 + lg * 8];
    #pragma unroll
    for (int i = 0; i < 4; ++i)
      #pragma unroll
      for (int j = 0; j < 4; ++j)
        acc[i][j] = __builtin_amdgcn_mfma_f32_16x16x32_bf16(av[i], bv[j], acc[i][j], 0, 0, 0);
  }
  #pragma unroll
  for (int j = 0; j < 4; ++j) {
    int n = n0 + wn + j * 16 + lr;
    float bias = b_ih[n] + b_hh[n];
    #pragma unroll
    for (int i = 0; i < 4; ++i) {
      #pragma unroll
      for (int r = 0; r < 4; ++r) {
        int m = m0 + wm + i * 16 + lg * 4 + r;
        int bb = m / 96;
        int tt = m - bb * 96;
        long row = (long)tt * 64 + bb;
        xg[row * 8192 + n] = f2bf(acc[i][j][r] + bias);
      }
    }
  }
}

// ---------------------------------------------------------------- recurrent step
// grid 256 (block cb: 4 gates x 8 h-cols = 32 W-rows, all 64 batches).
// Wave w owns K-slice [w*256,+256). K split into 4 chunks of 512:
//  - A (Hprev) staged per chunk into 2x64KB LDS ring (XOR-swizzled source,
//    linear dest); per chunk per wave: 8 ds_read_b128 feeding 16 MFMA
//    (a-frag reused across both b-frags) -> 1.3us LDS/CU/step.
//  - B (W_hh) loaded straight to VGPRs (4 bf16x8/chunk/wave), prefetched one
//    chunk ahead; W read exactly once grid-wide.
//  - counted vmcnt(12): next chunk's stage (8) + W prefetch (4) stay in
//    flight across the barrier; sched_barrier(0) pins issue order.
// 8 K-partials combined via 64KB LDS (aliases buf0) + fused gate/c/h epilogue.
__global__ __launch_bounds__(512) void lstm_step(
    const unsigned short* __restrict__ Whh,   // (8192,2048) bf16
    const unsigned short* __restrict__ xg,    // (96,64,8192) bf16
    const unsigned short* __restrict__ Hprev, // (64,2048) bf16
    unsigned short* __restrict__ Hnext,       // (64,2048) bf16
    unsigned short* __restrict__ Call_t,      // (64,2048) bf16 snapshot
    float* __restrict__ Cstate,               // (64,2048) f32
    int t) {
  extern __shared__ unsigned char smem[];     // 128 KB: buf0 64K | buf1 64K
  const int cb = blockIdx.x;
  const int tid = threadIdx.x;
  const int w = tid >> 6, l = tid & 63;
  const int lr = l & 15, lg = l >> 4;

  // ---- epilogue prefetch (oldest VMEM ops; complete before first wait)
  const int eb = tid >> 3;                    // batch 0..63
  const int ej = tid & 7;                     // col 0..7
  const unsigned short* xrow = xg + ((long)t * 64 + eb) * 8192 + cb * 8 + ej;
  const unsigned short x_i = xrow[0];
  const unsigned short x_f = xrow[2048];
  const unsigned short x_g = xrow[4096];
  const unsigned short x_o = xrow[6144];
  const long ci = (long)eb * 2048 + cb * 8 + ej;
  const float cprev = Cstate[ci];
  __builtin_amdgcn_sched_barrier(0);

  // ---- A staging: 8 gload_lds/thread/chunk; chunk = 64 rows x 1024B window
  // slot = i*512+tid; row = slot>>6; u = slot&63; src byte = (u*16)^((row&7)<<4)
#define STAGE(bufsel, c) do {                                                   \
    _Pragma("unroll")                                                           \
    for (int i_ = 0; i_ < 8; ++i_) {                                            \
      int slot_ = i_ * 512 + tid;                                               \
      int row_ = slot_ >> 6;                                                    \
      int ksrc_ = ((slot_ & 63) * 16) ^ ((row_ & 7) << 4);                      \
      const unsigned short* src_ =                                              \
          Hprev + (long)row_ * 2048 + (c) * 512 + (ksrc_ >> 1);                 \
      __builtin_amdgcn_global_load_lds((const AS1 unsigned int*)src_,           \
          (AS3 unsigned int*)(smem + (bufsel) * 65536 + slot_ * 16), 16, 0, 0); \
    }                                                                           \
    __builtin_amdgcn_sched_barrier(0);                                          \
  } while (0)

  // ---- W frags: row nn = nf*16+lr -> gate nf*2+(lr>>3), col cb*8+(lr&7)
  const long wr0 = ((long)(0 * 2 + (lr >> 3)) * 2048 + cb * 8 + (lr & 7)) * 2048;
  const long wr1 = ((long)(1 * 2 + (lr >> 3)) * 2048 + cb * 8 + (lr & 7)) * 2048;
  const int kwb = w * 64 + lg * 8;
#define LOAD_W(c, d00, d01, d10, d11) do {                                      \
    const unsigned short* wp_ = Whh + (long)(c) * 512 + kwb;                    \
    d00 = *(const bf16x8*)(wp_ + wr0);        /* nf=0 ksub=0 */                 \
    d01 = *(const bf16x8*)(wp_ + wr0 + 32);   /* nf=0 ksub=1 */                 \
    d10 = *(const bf16x8*)(wp_ + wr1);        /* nf=1 ksub=0 */                 \
    d11 = *(const bf16x8*)(wp_ + wr1 + 32);   /* nf=1 ksub=1 */                 \
    __builtin_amdgcn_sched_barrier(0);                                          \
  } while (0)

  // ---- per-chunk compute: 8 ds_read_b128 -> 16 MFMA (a reused x2)
  f32x4 acc[4][2] = {};
  const int kx = (lr & 7) << 4;
#define COMPUTE(bufsel, b00, b01, b10, b11) do {                                \
    const unsigned char* base_ = smem + (bufsel) * 65536;                       \
    __builtin_amdgcn_s_setprio(1);                                              \
    _Pragma("unroll")                                                           \
    for (int ksub_ = 0; ksub_ < 2; ++ksub_) {                                   \
      int kb_ = (w * 128 + ksub_ * 64 + lg * 16) ^ kx;                          \
      _Pragma("unroll")                                                         \
      for (int mf_ = 0; mf_ < 4; ++mf_) {                                       \
        bf16x8 a_ = *(const bf16x8*)(base_ + (mf_ * 16 + lr) * 1024 + kb_);     \
        acc[mf_][0] = __builtin_amdgcn_mfma_f32_16x16x32_bf16(                  \
            a_, ksub_ ? b01 : b00, acc[mf_][0], 0, 0, 0);                       \
        acc[mf_][1] = __builtin_amdgcn_mfma_f32_16x16x32_bf16(                  \
            a_, ksub_ ? b11 : b10, acc[mf_][1], 0, 0, 0);                       \
      }                                                                         \
    }                                                                           \
    __builtin_amdgcn_s_setprio(0);                                              \
    __builtin_amdgcn_sched_barrier(0);                                          \
  } while (0)

#define WAITN(n) do {                                                           \
    asm volatile("s_waitcnt vmcnt(" #n ")" ::: "memory");                       \
    __builtin_amdgcn_s_barrier();                                               \
    __builtin_amdgcn_sched_barrier(0);                                          \
  } while (0)

  bf16x8 c00, c01, c10, c11, n00, n01, n10, n11;

  LOAD_W(0, c00, c01, c10, c11);
  STAGE(0, 0);
  LOAD_W(1, n00, n01, n10, n11);
  STAGE(1, 1);

  WAITN(12);                 // stage0 done (newer: LW1 4 + stage1 8)
  COMPUTE(0, c00, c01, c10, c11);
  __builtin_amdgcn_s_barrier();  // buf0 free
  __builtin_amdgcn_sched_barrier(0);
  c00 = n00; c01 = n01; c10 = n10; c11 = n11;
  LOAD_W(2, n00, n01, n10, n11);
  STAGE(0, 2);

  WAITN(12);                 // stage1 done (newer: LW2 4 + stage2 8)
  COMPUTE(1, c00, c01, c10, c11);
  __builtin_amdgcn_s_barrier();  // buf1 free
  __builtin_amdgcn_sched_barrier(0);
  c00 = n00; c01 = n01; c10 = n10; c11 = n11;
  LOAD_W(3, n00, n01, n10, n11);
  STAGE(1, 3);

  WAITN(12);                 // stage2 done (newer: LW3 4 + stage3 8)
  COMPUTE(0, c00, c01, c10, c11);
  c00 = n00; c01 = n01; c10 = n10; c11 = n11;

  WAITN(0);                  // stage3 done
  COMPUTE(1, c00, c01, c10, c11);
  __syncthreads();           // all reads of buf0 done before partial overwrite

#undef STAGE
#undef LOAD_W
#undef COMPUTE
#undef WAITN

  // ---- K-partials -> LDS (alias buf0): part[w][nn:32][batch:64 ^ ((nn&7)<<3)]
  float* part = (float*)smem;
  #pragma unroll
  for (int nf = 0; nf < 2; ++nf) {
    const int nn = nf * 16 + lr;
    const int bsw = (lr & 7) << 3;
    #pragma unroll
    for (int mf = 0; mf < 4; ++mf) {
      const int b0 = (mf * 16 + lg * 4) ^ bsw;
      *(f32x4*)&part[(w * 32 + nn) * 64 + b0] = acc[mf][nf];
    }
  }
  __syncthreads();

  // ---- combine 8 K-partials + fused LSTM cell update
  float sum[4];
  #pragma unroll
  for (int g = 0; g < 4; ++g) {
    const int nn = g * 8 + ej;
    const int base = nn * 64 + (eb ^ (ej << 3));
    float s = 0.f;
    #pragma unroll
    for (int ww = 0; ww < 8; ++ww) s += part[ww * 2048 + base];
    sum[g] = s;
  }
  const float iv = sum[0] + bf2f(x_i);
  const float fv = sum[1] + bf2f(x_f);
  const float gv = sum[2] + bf2f(x_g);
  const float ov = sum[3] + bf2f(x_o);
  const float c = sigm(fv) * cprev + sigm(iv) * tanh_(gv);
  const float h = sigm(ov) * tanh_(c);
  Cstate[ci] = c;
  Call_t[ci] = f2bf(c);
  Hnext[ci] = f2bf(h);
}

// ---------------------------------------------------------------- heads (unchanged)
__global__ __launch_bounds__(256) void heads(
    const unsigned short* __restrict__ Hall,
    const unsigned short* __restrict__ Call,
    const float* __restrict__ Wp, const float* __restrict__ bp,
    const float* __restrict__ Wpc, const float* __restrict__ bpc,
    const float* __restrict__ Wu, const float* __restrict__ bu,
    const float* __restrict__ Wuse, const float* __restrict__ buse,
    const float* __restrict__ gum,
    float* __restrict__ out) {
  int p = blockIdx.x * 4 + (threadIdx.x >> 6);
  int l = threadIdx.x & 63;
  int t = p >> 6, b = p & 63;
  const unsigned short* h = Hall + ((long)(t + 1) * 64 + b) * 2048;
  const unsigned short* c = Call + ((long)t * 64 + b) * 2048;
  float s0 = 0, s1 = 0, sc0 = 0, sc1 = 0, su = 0, q0 = 0, q1 = 0;
  #pragma unroll
  for (int j = 0; j < 8; ++j) {
    int k = j * 256 + l * 4;
    ushort4 hv = *(const ushort4*)(h + k);
    ushort4 cv = *(const ushort4*)(c + k);
    float hf0 = bf2f(hv.x), hf1 = bf2f(hv.y), hf2 = bf2f(hv.z), hf3 = bf2f(hv.w);
    float cf0 = bf2f(cv.x), cf1 = bf2f(cv.y), cf2 = bf2f(cv.z), cf3 = bf2f(cv.w);
    float4 w0 = *(const float4*)(Wp + k);
    float4 w1 = *(const float4*)(Wp + 2048 + k);
    float4 w2 = *(const float4*)(Wpc + k);
    float4 w3 = *(const float4*)(Wpc + 2048 + k);
    float4 w4 = *(const float4*)(Wu + k);
    float4 w5 = *(const float4*)(Wuse + k);
    float4 w6 = *(const float4*)(Wuse + 2048 + k);
    s0 += hf0 * w0.x + hf1 * w0.y + hf2 * w0.z + hf3 * w0.w;
    s1 += hf0 * w1.x + hf1 * w1.y + hf2 * w1.z + hf3 * w1.w;
    sc0 += cf0 * w2.x + cf1 * w2.y + cf2 * w2.z + cf3 * w2.w;
    sc1 += cf0 * w3.x + cf1 * w3.y + cf2 * w3.z + cf3 * w3.w;
    su += hf0 * w4.x + hf1 * w4.y + hf2 * w4.z + hf3 * w4.w;
    q0 += hf0 * w5.x + hf1 * w5.y + hf2 * w5.z + hf3 * w5.w;
    q1 += hf0 * w6.x + hf1 * w6.y + hf2 * w6.z + hf3 * w6.w;
  }
  #pragma unroll
  for (int off = 32; off > 0; off >>= 1) {
    s0 += __shfl_xor(s0, off);
    s1 += __shfl_xor(s1, off);
    sc0 += __shfl_xor(sc0, off);
    sc1 += __shfl_xor(sc1, off);
    su += __shfl_xor(su, off);
    q0 += __shfl_xor(q0, off);
    q1 += __shfl_xor(q1, off);
  }
  if (l == 0) {
    out[(p << 1)] = s0 + bp[0];
    out[(p << 1) + 1] = s1 + bp[1];
    out[12288 + (p << 1)] = sc0 + bpc[0];
    out[12288 + (p << 1) + 1] = sc1 + bpc[1];
    out[24576 + p] = su + bu[0];
    float u0 = q0 + buse[0] + gum[p * 2];
    float u1 = q1 + buse[1] + gum[p * 2 + 1];
    float m = fmaxf(u0, u1);
    float x0 = expf(u0 - m), x1 = expf(u1 - m);
    float inv = 1.f / (x0 + x1);
    if (t >= 1) {
      out[30720 + ((t - 1) * 64 + b) * 2] = x0 * inv;
      out[30720 + ((t - 1) * 64 + b) * 2 + 1] = x1 * inv;
    }
  }
}

// ---------------------------------------------------------------- launch
extern "C" void kernel_launch(void* const* d_in, const int* in_sizes, int n_in,
                              void* d_out, int out_size, void* d_ws, size_t ws_size,
                              hipStream_t stream) {
  const float* feature  = (const float*)d_in[0];
  const float* W_ih     = (const float*)d_in[1];
  const float* W_hh     = (const float*)d_in[2];
  const float* b_ih     = (const float*)d_in[3];
  const float* b_hh     = (const float*)d_in[4];
  const float* W_pred   = (const float*)d_in[5];
  const float* b_pred   = (const float*)d_in[6];
  const float* W_pred_c = (const float*)d_in[7];
  const float* b_pred_c = (const float*)d_in[8];
  const float* W_util   = (const float*)d_in[9];
  const float* b_util   = (const float*)d_in[10];
  const float* W_use    = (const float*)d_in[11];
  const float* b_use    = (const float*)d_in[12];

  char* ws = (char*)d_ws;
  unsigned short* Abf  = (unsigned short*)(ws + 0);
  unsigned short* Call = (unsigned short*)(ws + 0);       // aliases Abf after phase 1
  unsigned short* Wbf  = (unsigned short*)(ws + 25165824L);
  unsigned short* xg   = (unsigned short*)(ws + 58720256L);
  unsigned short* Hall = (unsigned short*)(ws + 159383552L);
  float* Cstate        = (float*)(ws + 184811520L);
  float* gum           = (float*)(ws + 185335808L);
  float* out = (float*)d_out;

  hipMemsetAsync(Hall, 0, (size_t)BATCH * HID * 2, stream);
  hipMemsetAsync(Cstate, 0, (size_t)BATCH * HID * 4, stream);

  gumbel_k<<<48, 256, 0, stream>>>(gum);

  cast_bf16<<<(12582912 / 4) / 256, 256, 0, stream>>>(feature, Abf, 12582912 / 4);
  cast_bf16<<<(16777216 / 4) / 256, 256, 0, stream>>>(W_ih, Wbf, 16777216 / 4);

  gemm_xg<<<3072, 256, 0, stream>>>(Abf, Wbf, b_ih, b_hh, xg);

  cast_bf16<<<(16777216 / 4) / 256, 256, 0, stream>>>(W_hh, Wbf, 16777216 / 4);

  for (int t = 0; t < T_STEPS; ++t) {
    lstm_step<<<256, 512, 131072, stream>>>(
        Wbf, xg,
        Hall + (long)t * BATCH * HID,
        Hall + (long)(t + 1) * BATCH * HID,
        Call + (long)t * BATCH * HID,
        Cstate, t);
  }

  heads<<<1536, 256, 0, stream>>>(Hall, Call,
                                  W_pred, b_pred, W_pred_c, b_pred_c,
                                  W_util, b_util, W_use, b_use,
                                  gum, out);
}